// Round 24
// baseline (31.838 us; speedup 1.0000x reference)
//
#include <hip/hip_runtime.h>
#include <math.h>

#define HH 384
#define WW 384
#define HWSZ (HH * WW)
#define NPIX (2 * HWSZ)
#define KSEL 11
#define TW 48                  // tile width
#define TH 12                  // tile height (4-wave block, pooled list)
#define PXB (TW * TH)          // 576 interior px = 9*64 exactly
#define NTHR 256               // 4 waves
#define NW 4
#define NCH 9                  // 576/64 compaction chunks
#define TPW (TW + 10)          // 58
#define TPH (TH + 10)          // 22
#define TILE_N (TPW * TPH)     // 1276 float4 (~20.4 KB)
#define NBX (WW / TW)          // 8
#define NBY (HH / TH)          // 32
#define NBLK (2 * NBX * NBY)   // 512 = exactly 2 blocks/CU
#define NGRP 32                // arrival-tree groups (16 blocks each)
#define CTR_STRIDE 16          // u32 stride between group counters (64 B)

__device__ __forceinline__ float fast_sqrtf(float x) {
    float r;
    asm("v_sqrt_f32 %0, %1" : "=v"(r) : "v"(x));
    return r;
}

__device__ __forceinline__ float wave_sum(float v) {
#pragma unroll
    for (int off = 32; off > 0; off >>= 1) v += __shfl_down(v, off, 64);
    return v;
}

// Key: high 20 bits = d^2 (f32 bits truncated), low 12 = pre-quantized
// neighbor alpha. d2 >= 0 so float min/max order == lexicographic.
__device__ __forceinline__ float make_key(const float4 c, const float4 n) {
    const float e0 = c.x - n.x;
    const float e1 = c.y - n.y;
    const float e2 = c.z - n.z;
    float d2 = e0 * e0;
    d2 = __builtin_fmaf(e1, e1, d2);
    d2 = __builtin_fmaf(e2, e2, d2);
    const unsigned bits = (__float_as_uint(d2) & 0xFFFFF000u) | __float_as_uint(n.w);
    return __uint_as_float(bits);
}

// Merge an unsorted pair into sorted-ascending bd[0..10], keep smallest 11.
__device__ __forceinline__ void merge2(float bd[KSEL], float a, float b) {
    const float p0 = fminf(a, b);
    const float p1 = fmaxf(a, b);
    float nb[KSEL];
    nb[0] = fminf(bd[0], p0);
    nb[1] = fminf(fminf(bd[1], fmaxf(bd[0], p0)), p1);
#pragma unroll
    for (int j = 2; j < KSEL; ++j)
        nb[j] = fminf(fminf(bd[j], fmaxf(bd[j - 1], p0)), fmaxf(bd[j - 2], p1));
#pragma unroll
    for (int j = 0; j < KSEL; ++j) bd[j] = nb[j];
}

__device__ __forceinline__ void merge1(float bd[KSEL], float p) {
    float cd = p;
#pragma unroll
    for (int j = 0; j < KSEL; ++j) {
        const float mx = fmaxf(cd, bd[j]);
        bd[j] = fminf(cd, bd[j]);
        cd = mx;
    }
}

__device__ __forceinline__ float acc_ddc(const float bd[KSEL], float ac) {
    float s = 0.f;
#pragma unroll
    for (int j = 0; j < KSEL; ++j) {
        const unsigned kb = __float_as_uint(bd[j]);
        const float d2 = __uint_as_float((kb & 0xFFFFF000u) | 0x800u); // midpoint
        const float ad = __builtin_fmaf((float)(kb & 0xFFFu), -1.0f / 4095.0f, ac);
        s += fabsf(fast_sqrtf(d2) - ad);
    }
    return s;
}

// Pin a float4 into live VGPRs (defeats the rematerializer — R21's
// VGPR_Count=24 proved unpinned batches dissolve to serial load->use).
#define KEEP4(v) asm volatile("" : "+v"((v).x), "+v"((v).y), "+v"((v).z), "+v"((v).w))

__global__ __launch_bounds__(NTHR, 2) void matting_main(
    const float* __restrict__ alpha,
    const float* __restrict__ trimap,
    const float* __restrict__ image,
    float4* __restrict__ bout,      // one float4 per block
    unsigned* __restrict__ ctr,     // NGRP padded group ctrs + master
    float* __restrict__ out)
{
    __shared__ float4 tile[TILE_N];          // denorm rgb + quantized-alpha bits
    __shared__ float aex[PXB];               // exact alpha, interior px
    __shared__ unsigned short list[PXB];     // block-pooled unknown px
    __shared__ unsigned long long chMask[NCH];
    __shared__ float4 bred[NW];
    __shared__ int lastFlag;

    const int tid = (int)threadIdx.x;
    const int lane = tid & 63;
    const int w    = tid >> 6;
    const int bx  = blockIdx.x % NBX;
    const int byy = (blockIdx.x / NBX) % NBY;
    const int b   = blockIdx.x / (NBX * NBY);

    const float* i0 = image + b * 3 * HWSZ;
    const float* i1 = i0 + HWSZ;
    const float* i2 = i1 + HWSZ;
    const float* ap = alpha + b * HWSZ;
    const float* tm = trimap + b * HWSZ;

    const int row0 = byy * TH, col0 = bx * TW;
    const int gy0 = row0 - 5, gx0 = col0 - 5;

    // ---- stage padded denormalized tile (zero pad == reference's unfold pad)
    for (int t = tid; t < TILE_N; t += NTHR) {
        const int ry = t / TPW, rx = t - ry * TPW;
        const int gy = gy0 + ry, gx = gx0 + rx;
        float4 v = make_float4(0.f, 0.f, 0.f, 0.f);
        if ((unsigned)gy < (unsigned)HH && (unsigned)gx < (unsigned)WW) {
            const int gi = gy * WW + gx;
            v.x = __builtin_fmaf(i0[gi], 0.229f, 0.485f);
            v.y = __builtin_fmaf(i1[gi], 0.224f, 0.456f);
            v.z = __builtin_fmaf(i2[gi], 0.225f, 0.406f);
            v.w = __uint_as_float((unsigned)(ap[gi] * 4095.0f)); // payload bits
        }
        tile[t] = v;
    }

    // ---- compaction ballots over 9 exact chunks (576 = 9*64, no masking) ----
    float kv = 0.f;
    for (int ch = w; ch < NCH; ch += NW) {
        const int p = ch * 64 + lane;
        const int r = p / TW, cc = p - r * TW;
        const int gi = (row0 + r) * WW + col0 + cc;
        const float a = ap[gi];
        const float tri = tm[gi];
        aex[p] = a;
        const bool unk = (tri == 0.5f);
        kv += unk ? 0.f : fabsf(a - tri);
        const unsigned long long m = __ballot(unk);
        if (lane == 0) chMask[ch] = m;
    }
    __syncthreads();

    // ---- deterministic scatter (prefix over chunk counts) ----
    unsigned pre[NCH + 1];
    pre[0] = 0;
#pragma unroll
    for (int c = 0; c < NCH; ++c) pre[c + 1] = pre[c] + (unsigned)__popcll(chMask[c]);
    const unsigned cnt = pre[NCH];
    for (int ch = w; ch < NCH; ch += NW) {
        const unsigned long long m = chMask[ch];
        if ((m >> lane) & 1ull) {
            const int p = ch * 64 + lane;
            const int r = p / TW, cc = p - r * TW;
            list[pre[ch] + (unsigned)__popcll(m & ((1ull << lane) - 1ull))] =
                (unsigned short)((r << 6) | cc);
        }
    }
    __syncthreads();

    // ---- selection: waves claim interleaved 64-rounds of the block pool ----
    float wdsum = 0.f;
    for (unsigned start = (unsigned)w * 64u; start < cnt; start += (unsigned)NTHR) {
        const unsigned i = start + (unsigned)lane;
        const bool act = i < cnt;
        if (act) {
            const unsigned e = (unsigned)list[i];
            const int r = (int)(e >> 6), cc = (int)(e & 63u);

            const float4* tp = &tile[r * TPW + cc];
            const float4 c4 = tp[5 * TPW + 5];
            const float ac = aex[r * TW + cc];

            float bd[KSEL];
#pragma unroll
            for (int j = 0; j < KSEL; ++j) bd[j] = __uint_as_float(0x7F800000u);

#pragma unroll
            for (int di = 0; di < 11; ++di) {
                const float4* row = tp + di * TPW;
                // Batch the 11 row loads into pinned registers: all issue
                // back-to-back, one waitcnt covers them, merges consume regs.
                float4 rb[11];
#pragma unroll
                for (int h = 0; h < 11; ++h) rb[h] = row[h];
#pragma unroll
                for (int h = 0; h < 11; ++h) KEEP4(rb[h]);

                float k[11];
#pragma unroll
                for (int h = 0; h < 11; ++h) k[h] = make_key(c4, rb[h]);
#pragma unroll
                for (int h = 0; h < 5; ++h) merge2(bd, k[2 * h], k[2 * h + 1]);
                merge1(bd, k[10]);
            }

            wdsum += acc_ddc(bd, ac);
        }
    }

    // ---- block partial ----
    const float vkv = wave_sum(kv);
    const float vds = wave_sum(wdsum);
    if (lane == 0) bred[w] = make_float4(vkv, vds, 0.f, 0.f);
    __syncthreads();

    // ---- hierarchical arrival tree (32 groups x 16 blocks; max serial
    // atomic chain = 16 + 32 at ~12 ns each — vs R10's 1024 = 12.3 us) ----
    if (tid == 0) {
        const float ks = bred[0].x + bred[1].x + bred[2].x + bred[3].x;
        const float ds = bred[0].y + bred[1].y + bred[2].y + bred[3].y;
        bout[blockIdx.x] = make_float4(ks, ds, (float)cnt, 0.f);
        __threadfence();                              // partial visible device-wide
        const unsigned g = (unsigned)blockIdx.x & (NGRP - 1);
        int lf = 0;
        const unsigned old = atomicAdd(&ctr[g * CTR_STRIDE], 1u);
        if (old == (unsigned)(NBLK / NGRP - 1)) {     // group complete
            ctr[g * CTR_STRIDE] = 0u;                 // self-reset for replay
            const unsigned m = atomicAdd(&ctr[NGRP * CTR_STRIDE], 1u);
            lf = (m == (unsigned)(NGRP - 1)) ? 1 : 0;
        }
        lastFlag = lf;
    }
    __syncthreads();

    // ---- last-arriving block: fixed-order final reduction (deterministic
    // regardless of which block executes it) ----
    if (lastFlag) {
        __threadfence();                              // acquire all partials
        float ks = 0.f, ds = 0.f, un = 0.f;
#pragma unroll
        for (int q = 0; q < NBLK / NTHR; ++q) {       // 2 float4 per thread
            const float4 v = bout[q * NTHR + tid];
            ks += v.x; ds += v.y; un += v.z;
        }
        ks = wave_sum(ks); ds = wave_sum(ds); un = wave_sum(un);
        if (lane == 0) bred[w] = make_float4(ks, ds, un, 0.f);
        __syncthreads();
        if (tid == 0) {
            float ksum = 0.f, dsum = 0.f, ucnt = 0.f;
#pragma unroll
            for (int q = 0; q < NW; ++q) {
                ksum += bred[q].x; dsum += bred[q].y; ucnt += bred[q].z;
            }
            const float kcnt = (float)NPIX - ucnt;
            const float known = (kcnt > 0.f) ? ksum * (1.0f / (float)NPIX) : 0.f;
            const float ddc   = (ucnt > 0.f) ? dsum * (0.1f / ((float)NPIX * (float)KSEL)) : 0.f;
            out[0] = known + ddc;
            out[1] = known;
            out[2] = ddc;
            ctr[NGRP * CTR_STRIDE] = 0u;              // self-reset master
        }
    }
}

extern "C" void kernel_launch(void* const* d_in, const int* in_sizes, int n_in,
                              void* d_out, int out_size, void* d_ws, size_t ws_size,
                              hipStream_t stream) {
    const float* alpha  = (const float*)d_in[0];  // pred_alpha  [2,1,384,384]
    const float* trimap = (const float*)d_in[1];  // gt_trimap   [2,1,384,384]
    const float* image  = (const float*)d_in[2];  // input_image [2,3,384,384]
    float* out = (float*)d_out;

    float4*   bout = (float4*)d_ws;                              // NBLK float4
    unsigned* ctr  = (unsigned*)((char*)d_ws + NBLK * 16);       // counters

    hipMemsetAsync(ctr, 0, (NGRP * CTR_STRIDE + 1) * 4, stream); // graph-safe
    matting_main<<<NBLK, NTHR, 0, stream>>>(alpha, trimap, image, bout, ctr, out);
}

// Round 25
// 21.065 us; speedup vs baseline: 1.5114x; 1.5114x over previous
//
#include <hip/hip_runtime.h>
#include <math.h>

#define HH 384
#define WW 384
#define HWSZ (HH * WW)
#define NPIX (2 * HWSZ)
#define KSEL 11
#define TW 48                  // tile width
#define TH 12                  // tile height (4-wave block, pooled list)
#define PXB (TW * TH)          // 576 interior px = 9*64 exactly
#define NTHR 256               // 4 waves
#define NW 4
#define NCH 9                  // 576/64 compaction chunks
#define TPW (TW + 10)          // 58
#define TPH (TH + 10)          // 22
#define TILE_N (TPW * TPH)     // 1276 float4 (~20.4 KB)
#define NBX (WW / TW)          // 8
#define NBY (HH / TH)          // 32
#define NBLK (2 * NBX * NBY)   // 512 = exactly 2 blocks/CU

__device__ __forceinline__ float fast_sqrtf(float x) {
    float r;
    asm("v_sqrt_f32 %0, %1" : "=v"(r) : "v"(x));
    return r;
}

__device__ __forceinline__ float wave_sum(float v) {
#pragma unroll
    for (int off = 32; off > 0; off >>= 1) v += __shfl_down(v, off, 64);
    return v;
}

// Key: high 20 bits = d^2 (f32 bits truncated), low 12 = pre-quantized
// neighbor alpha. d2 >= 0 so float min/max order == lexicographic.
__device__ __forceinline__ float make_key(const float4 c, const float4 n) {
    const float e0 = c.x - n.x;
    const float e1 = c.y - n.y;
    const float e2 = c.z - n.z;
    float d2 = e0 * e0;
    d2 = __builtin_fmaf(e1, e1, d2);
    d2 = __builtin_fmaf(e2, e2, d2);
    const unsigned bits = (__float_as_uint(d2) & 0xFFFFF000u) | __float_as_uint(n.w);
    return __uint_as_float(bits);
}

// Merge an unsorted pair into sorted-ascending bd[0..10], keep smallest 11.
__device__ __forceinline__ void merge2(float bd[KSEL], float a, float b) {
    const float p0 = fminf(a, b);
    const float p1 = fmaxf(a, b);
    float nb[KSEL];
    nb[0] = fminf(bd[0], p0);
    nb[1] = fminf(fminf(bd[1], fmaxf(bd[0], p0)), p1);
#pragma unroll
    for (int j = 2; j < KSEL; ++j)
        nb[j] = fminf(fminf(bd[j], fmaxf(bd[j - 1], p0)), fmaxf(bd[j - 2], p1));
#pragma unroll
    for (int j = 0; j < KSEL; ++j) bd[j] = nb[j];
}

__device__ __forceinline__ void merge1(float bd[KSEL], float p) {
    float cd = p;
#pragma unroll
    for (int j = 0; j < KSEL; ++j) {
        const float mx = fmaxf(cd, bd[j]);
        bd[j] = fminf(cd, bd[j]);
        cd = mx;
    }
}

__device__ __forceinline__ float acc_ddc(const float bd[KSEL], float ac) {
    float s = 0.f;
#pragma unroll
    for (int j = 0; j < KSEL; ++j) {
        const unsigned kb = __float_as_uint(bd[j]);
        const float d2 = __uint_as_float((kb & 0xFFFFF000u) | 0x800u); // midpoint
        const float ad = __builtin_fmaf((float)(kb & 0xFFFu), -1.0f / 4095.0f, ac);
        s += fabsf(fast_sqrtf(d2) - ad);
    }
    return s;
}

// Force a float4 to be materialized in VGPRs at this program point. This is
// the one tool that defeats the register-minimizing rematerializer (R21's
// VGPR_Count=24 proved all prior batching structures were dissolved into
// serial load->use pairs, each eating full exposed LDS latency).
#define KEEP4(v) asm volatile("" : "+v"((v).x), "+v"((v).y), "+v"((v).z), "+v"((v).w))

__global__ __launch_bounds__(NTHR, 2) void matting_main(
    const float* __restrict__ alpha,
    const float* __restrict__ trimap,
    const float* __restrict__ image,
    float4* __restrict__ bout)      // one float4 per block
{
    __shared__ float4 tile[TILE_N];          // denorm rgb + quantized-alpha bits
    __shared__ float aex[PXB];               // exact alpha, interior px
    __shared__ unsigned short list[PXB];     // block-pooled unknown px
    __shared__ unsigned long long chMask[NCH];
    __shared__ float4 bred[NW];

    const int tid = (int)threadIdx.x;
    const int lane = tid & 63;
    const int w    = tid >> 6;
    const int bx  = blockIdx.x % NBX;
    const int byy = (blockIdx.x / NBX) % NBY;
    const int b   = blockIdx.x / (NBX * NBY);

    const float* i0 = image + b * 3 * HWSZ;
    const float* i1 = i0 + HWSZ;
    const float* i2 = i1 + HWSZ;
    const float* ap = alpha + b * HWSZ;
    const float* tm = trimap + b * HWSZ;

    const int row0 = byy * TH, col0 = bx * TW;
    const int gy0 = row0 - 5, gx0 = col0 - 5;

    // ---- stage padded denormalized tile (zero pad == reference's unfold pad)
    for (int t = tid; t < TILE_N; t += NTHR) {
        const int ry = t / TPW, rx = t - ry * TPW;
        const int gy = gy0 + ry, gx = gx0 + rx;
        float4 v = make_float4(0.f, 0.f, 0.f, 0.f);
        if ((unsigned)gy < (unsigned)HH && (unsigned)gx < (unsigned)WW) {
            const int gi = gy * WW + gx;
            v.x = __builtin_fmaf(i0[gi], 0.229f, 0.485f);
            v.y = __builtin_fmaf(i1[gi], 0.224f, 0.456f);
            v.z = __builtin_fmaf(i2[gi], 0.225f, 0.406f);
            v.w = __uint_as_float((unsigned)(ap[gi] * 4095.0f)); // payload bits
        }
        tile[t] = v;
    }

    // ---- compaction ballots over 9 exact chunks (576 = 9*64, no masking) ----
    float kv = 0.f;
    for (int ch = w; ch < NCH; ch += NW) {
        const int p = ch * 64 + lane;
        const int r = p / TW, cc = p - r * TW;
        const int gi = (row0 + r) * WW + col0 + cc;
        const float a = ap[gi];
        const float tri = tm[gi];
        aex[p] = a;
        const bool unk = (tri == 0.5f);
        kv += unk ? 0.f : fabsf(a - tri);
        const unsigned long long m = __ballot(unk);
        if (lane == 0) chMask[ch] = m;
    }
    __syncthreads();

    // ---- deterministic scatter (prefix over chunk counts) ----
    unsigned pre[NCH + 1];
    pre[0] = 0;
#pragma unroll
    for (int c = 0; c < NCH; ++c) pre[c + 1] = pre[c] + (unsigned)__popcll(chMask[c]);
    const unsigned cnt = pre[NCH];
    for (int ch = w; ch < NCH; ch += NW) {
        const unsigned long long m = chMask[ch];
        if ((m >> lane) & 1ull) {
            const int p = ch * 64 + lane;
            const int r = p / TW, cc = p - r * TW;
            list[pre[ch] + (unsigned)__popcll(m & ((1ull << lane) - 1ull))] =
                (unsigned short)((r << 6) | cc);
        }
    }
    __syncthreads();

    // ---- selection: waves claim interleaved 64-rounds of the block pool ----
    float wdsum = 0.f;
    for (unsigned start = (unsigned)w * 64u; start < cnt; start += (unsigned)NTHR) {
        const unsigned i = start + (unsigned)lane;
        const bool act = i < cnt;
        if (act) {
            const unsigned e = (unsigned)list[i];
            const int r = (int)(e >> 6), cc = (int)(e & 63u);

            const float4* tp = &tile[r * TPW + cc];
            const float4 c4 = tp[5 * TPW + 5];
            const float ac = aex[r * TW + cc];

            float bd[KSEL];
#pragma unroll
            for (int j = 0; j < KSEL; ++j) bd[j] = __uint_as_float(0x7F800000u);

#pragma unroll
            for (int di = 0; di < 11; ++di) {
                const float4* row = tp + di * TPW;
                // Batch the 11 row loads into pinned registers: all issue
                // back-to-back, one waitcnt covers them, merges consume regs.
                float4 rb[11];
#pragma unroll
                for (int h = 0; h < 11; ++h) rb[h] = row[h];
#pragma unroll
                for (int h = 0; h < 11; ++h) KEEP4(rb[h]);

                float k[11];
#pragma unroll
                for (int h = 0; h < 11; ++h) k[h] = make_key(c4, rb[h]);
#pragma unroll
                for (int h = 0; h < 5; ++h) merge2(bd, k[2 * h], k[2 * h + 1]);
                merge1(bd, k[10]);
            }

            wdsum += acc_ddc(bd, ac);
        }
    }

    // ---- block-level reduction: one float4 per block ----
    const float vkv = wave_sum(kv);
    const float vds = wave_sum(wdsum);
    if (lane == 0) bred[w] = make_float4(vkv, vds, 0.f, 0.f);
    __syncthreads();
    if (tid == 0) {
        const float ks = bred[0].x + bred[1].x + bred[2].x + bred[3].x;
        const float ds = bred[0].y + bred[1].y + bred[2].y + bred[3].y;
        bout[blockIdx.x] = make_float4(ks, ds, (float)cnt, 0.f);
    }
}

__global__ __launch_bounds__(256) void matting_finalize(
    const float4* __restrict__ bout, float* __restrict__ out)
{
    float ks = 0.f, ds = 0.f, un = 0.f;
#pragma unroll
    for (int q = 0; q < NBLK / 256; ++q) {           // 2 float4 per thread
        const float4 v = bout[q * 256 + (int)threadIdx.x];
        ks += v.x; ds += v.y; un += v.z;
    }
    ks = wave_sum(ks); ds = wave_sum(ds); un = wave_sum(un);
    __shared__ float sred[4][3];
    const int wid = threadIdx.x >> 6, lane = threadIdx.x & 63;
    if (lane == 0) { sred[wid][0] = ks; sred[wid][1] = ds; sred[wid][2] = un; }
    __syncthreads();
    if (threadIdx.x == 0) {
        float ksum = 0, dsum = 0, ucnt = 0;
#pragma unroll
        for (int q = 0; q < 4; ++q) {
            ksum += sred[q][0]; dsum += sred[q][1]; ucnt += sred[q][2];
        }
        const float kcnt = (float)NPIX - ucnt;
        const float known = (kcnt > 0.f) ? ksum * (1.0f / (float)NPIX) : 0.f;
        const float ddc   = (ucnt > 0.f) ? dsum * (0.1f / ((float)NPIX * (float)KSEL)) : 0.f;
        out[0] = known + ddc;
        out[1] = known;
        out[2] = ddc;
    }
}

extern "C" void kernel_launch(void* const* d_in, const int* in_sizes, int n_in,
                              void* d_out, int out_size, void* d_ws, size_t ws_size,
                              hipStream_t stream) {
    const float* alpha  = (const float*)d_in[0];  // pred_alpha  [2,1,384,384]
    const float* trimap = (const float*)d_in[1];  // gt_trimap   [2,1,384,384]
    const float* image  = (const float*)d_in[2];  // input_image [2,3,384,384]
    float* out = (float*)d_out;
    float4* bout = (float4*)d_ws;                 // NBLK float4 partials

    matting_main<<<NBLK, NTHR, 0, stream>>>(alpha, trimap, image, bout);
    matting_finalize<<<1, 256, 0, stream>>>(bout, out);
}

// Round 26
// 21.020 us; speedup vs baseline: 1.5146x; 1.0021x over previous
//
#include <hip/hip_runtime.h>
#include <math.h>

#define HH 384
#define WW 384
#define HWSZ (HH * WW)
#define NPIX (2 * HWSZ)
#define KSEL 11
#define TW 48                  // tile width
#define TH 12                  // tile height (4-wave block, pooled list)
#define PXB (TW * TH)          // 576 interior px = 9*64 exactly
#define NTHR 256               // 4 waves
#define NW 4
#define NCH 9                  // 576/64 compaction chunks
#define TPW (TW + 10)          // 58
#define TPH (TH + 10)          // 22
#define TILE_N (TPW * TPH)     // 1276 float4 (~20.4 KB)
#define NBX (WW / TW)          // 8
#define NBY (HH / TH)          // 32
#define NBLK (2 * NBX * NBY)   // 512 = exactly 2 blocks/CU

__device__ __forceinline__ float fast_sqrtf(float x) {
    float r;
    asm("v_sqrt_f32 %0, %1" : "=v"(r) : "v"(x));
    return r;
}

__device__ __forceinline__ float wave_sum(float v) {
#pragma unroll
    for (int off = 32; off > 0; off >>= 1) v += __shfl_down(v, off, 64);
    return v;
}

// Key: high 20 bits = d^2 (f32 bits truncated), low 12 = pre-quantized
// neighbor alpha. d2 >= 0 so float min/max order == lexicographic.
__device__ __forceinline__ float make_key(const float4 c, const float4 n) {
    const float e0 = c.x - n.x;
    const float e1 = c.y - n.y;
    const float e2 = c.z - n.z;
    float d2 = e0 * e0;
    d2 = __builtin_fmaf(e1, e1, d2);
    d2 = __builtin_fmaf(e2, e2, d2);
    const unsigned bits = (__float_as_uint(d2) & 0xFFFFF000u) | __float_as_uint(n.w);
    return __uint_as_float(bits);
}

// Merge an unsorted pair into sorted-ascending bd[0..10], keep smallest 11.
__device__ __forceinline__ void merge2(float bd[KSEL], float a, float b) {
    const float p0 = fminf(a, b);
    const float p1 = fmaxf(a, b);
    float nb[KSEL];
    nb[0] = fminf(bd[0], p0);
    nb[1] = fminf(fminf(bd[1], fmaxf(bd[0], p0)), p1);
#pragma unroll
    for (int j = 2; j < KSEL; ++j)
        nb[j] = fminf(fminf(bd[j], fmaxf(bd[j - 1], p0)), fmaxf(bd[j - 2], p1));
#pragma unroll
    for (int j = 0; j < KSEL; ++j) bd[j] = nb[j];
}

__device__ __forceinline__ void merge1(float bd[KSEL], float p) {
    float cd = p;
#pragma unroll
    for (int j = 0; j < KSEL; ++j) {
        const float mx = fmaxf(cd, bd[j]);
        bd[j] = fminf(cd, bd[j]);
        cd = mx;
    }
}

__device__ __forceinline__ float acc_ddc(const float bd[KSEL], float ac) {
    float s = 0.f;
#pragma unroll
    for (int j = 0; j < KSEL; ++j) {
        const unsigned kb = __float_as_uint(bd[j]);
        const float d2 = __uint_as_float((kb & 0xFFFFF000u) | 0x800u); // midpoint
        const float ad = __builtin_fmaf((float)(kb & 0xFFFu), -1.0f / 4095.0f, ac);
        s += fabsf(fast_sqrtf(d2) - ad);
    }
    return s;
}

// Pin values into live VGPRs (defeats the rematerializer — R21's VGPR_Count=24
// proved unpinned batches dissolve to serial load->use/compute->use chains,
// each eating full dependent latency on the critical path).
#define KEEP4(v) asm volatile("" : "+v"((v).x), "+v"((v).y), "+v"((v).z), "+v"((v).w))
#define KEEP1(v) asm volatile("" : "+v"(v))

__global__ __launch_bounds__(NTHR, 2) void matting_main(
    const float* __restrict__ alpha,
    const float* __restrict__ trimap,
    const float* __restrict__ image,
    float4* __restrict__ bout)      // one float4 per block
{
    __shared__ float4 tile[TILE_N];          // denorm rgb + quantized-alpha bits
    __shared__ float aex[PXB];               // exact alpha, interior px
    __shared__ unsigned short list[PXB];     // block-pooled unknown px
    __shared__ unsigned long long chMask[NCH];
    __shared__ float4 bred[NW];

    const int tid = (int)threadIdx.x;
    const int lane = tid & 63;
    const int w    = tid >> 6;
    const int bx  = blockIdx.x % NBX;
    const int byy = (blockIdx.x / NBX) % NBY;
    const int b   = blockIdx.x / (NBX * NBY);

    const float* i0 = image + b * 3 * HWSZ;
    const float* i1 = i0 + HWSZ;
    const float* i2 = i1 + HWSZ;
    const float* ap = alpha + b * HWSZ;
    const float* tm = trimap + b * HWSZ;

    const int row0 = byy * TH, col0 = bx * TW;
    const int gy0 = row0 - 5, gx0 = col0 - 5;

    // ---- stage padded denormalized tile (zero pad == reference's unfold pad)
    for (int t = tid; t < TILE_N; t += NTHR) {
        const int ry = t / TPW, rx = t - ry * TPW;
        const int gy = gy0 + ry, gx = gx0 + rx;
        float4 v = make_float4(0.f, 0.f, 0.f, 0.f);
        if ((unsigned)gy < (unsigned)HH && (unsigned)gx < (unsigned)WW) {
            const int gi = gy * WW + gx;
            v.x = __builtin_fmaf(i0[gi], 0.229f, 0.485f);
            v.y = __builtin_fmaf(i1[gi], 0.224f, 0.456f);
            v.z = __builtin_fmaf(i2[gi], 0.225f, 0.406f);
            v.w = __uint_as_float((unsigned)(ap[gi] * 4095.0f)); // payload bits
        }
        tile[t] = v;
    }

    // ---- compaction ballots over 9 exact chunks (576 = 9*64, no masking) ----
    float kv = 0.f;
    for (int ch = w; ch < NCH; ch += NW) {
        const int p = ch * 64 + lane;
        const int r = p / TW, cc = p - r * TW;
        const int gi = (row0 + r) * WW + col0 + cc;
        const float a = ap[gi];
        const float tri = tm[gi];
        aex[p] = a;
        const bool unk = (tri == 0.5f);
        kv += unk ? 0.f : fabsf(a - tri);
        const unsigned long long m = __ballot(unk);
        if (lane == 0) chMask[ch] = m;
    }
    __syncthreads();

    // ---- deterministic scatter (prefix over chunk counts) ----
    unsigned pre[NCH + 1];
    pre[0] = 0;
#pragma unroll
    for (int c = 0; c < NCH; ++c) pre[c + 1] = pre[c] + (unsigned)__popcll(chMask[c]);
    const unsigned cnt = pre[NCH];
    for (int ch = w; ch < NCH; ch += NW) {
        const unsigned long long m = chMask[ch];
        if ((m >> lane) & 1ull) {
            const int p = ch * 64 + lane;
            const int r = p / TW, cc = p - r * TW;
            list[pre[ch] + (unsigned)__popcll(m & ((1ull << lane) - 1ull))] =
                (unsigned short)((r << 6) | cc);
        }
    }
    __syncthreads();

    // ---- selection: waves claim interleaved 64-rounds of the block pool ----
    float wdsum = 0.f;
    for (unsigned start = (unsigned)w * 64u; start < cnt; start += (unsigned)NTHR) {
        const unsigned i = start + (unsigned)lane;
        const bool act = i < cnt;
        if (act) {
            const unsigned e = (unsigned)list[i];
            const int r = (int)(e >> 6), cc = (int)(e & 63u);

            const float4* tp = &tile[r * TPW + cc];
            const float4 c4 = tp[5 * TPW + 5];
            const float ac = aex[r * TW + cc];

            float bd[KSEL];
#pragma unroll
            for (int j = 0; j < KSEL; ++j) bd[j] = __uint_as_float(0x7F800000u);

#pragma unroll
            for (int di = 0; di < 11; ++di) {
                const float4* row = tp + di * TPW;
                // Batch the 11 row loads into pinned registers: all issue
                // back-to-back, one waitcnt covers them.
                float4 rb[11];
#pragma unroll
                for (int h = 0; h < 11; ++h) rb[h] = row[h];
#pragma unroll
                for (int h = 0; h < 11; ++h) KEEP4(rb[h]);

                // Compute ALL 11 keys, then pin them: forces the 11
                // independent make_key chains to overlap instead of being
                // rematerialized serially before each merge (R26 variable).
                float k[11];
#pragma unroll
                for (int h = 0; h < 11; ++h) k[h] = make_key(c4, rb[h]);
#pragma unroll
                for (int h = 0; h < 11; ++h) KEEP1(k[h]);

#pragma unroll
                for (int h = 0; h < 5; ++h) merge2(bd, k[2 * h], k[2 * h + 1]);
                merge1(bd, k[10]);
            }

            wdsum += acc_ddc(bd, ac);
        }
    }

    // ---- block-level reduction: one float4 per block ----
    const float vkv = wave_sum(kv);
    const float vds = wave_sum(wdsum);
    if (lane == 0) bred[w] = make_float4(vkv, vds, 0.f, 0.f);
    __syncthreads();
    if (tid == 0) {
        const float ks = bred[0].x + bred[1].x + bred[2].x + bred[3].x;
        const float ds = bred[0].y + bred[1].y + bred[2].y + bred[3].y;
        bout[blockIdx.x] = make_float4(ks, ds, (float)cnt, 0.f);
    }
}

__global__ __launch_bounds__(256) void matting_finalize(
    const float4* __restrict__ bout, float* __restrict__ out)
{
    float ks = 0.f, ds = 0.f, un = 0.f;
#pragma unroll
    for (int q = 0; q < NBLK / 256; ++q) {           // 2 float4 per thread
        const float4 v = bout[q * 256 + (int)threadIdx.x];
        ks += v.x; ds += v.y; un += v.z;
    }
    ks = wave_sum(ks); ds = wave_sum(ds); un = wave_sum(un);
    __shared__ float sred[4][3];
    const int wid = threadIdx.x >> 6, lane = threadIdx.x & 63;
    if (lane == 0) { sred[wid][0] = ks; sred[wid][1] = ds; sred[wid][2] = un; }
    __syncthreads();
    if (threadIdx.x == 0) {
        float ksum = 0, dsum = 0, ucnt = 0;
#pragma unroll
        for (int q = 0; q < 4; ++q) {
            ksum += sred[q][0]; dsum += sred[q][1]; ucnt += sred[q][2];
        }
        const float kcnt = (float)NPIX - ucnt;
        const float known = (kcnt > 0.f) ? ksum * (1.0f / (float)NPIX) : 0.f;
        const float ddc   = (ucnt > 0.f) ? dsum * (0.1f / ((float)NPIX * (float)KSEL)) : 0.f;
        out[0] = known + ddc;
        out[1] = known;
        out[2] = ddc;
    }
}

extern "C" void kernel_launch(void* const* d_in, const int* in_sizes, int n_in,
                              void* d_out, int out_size, void* d_ws, size_t ws_size,
                              hipStream_t stream) {
    const float* alpha  = (const float*)d_in[0];  // pred_alpha  [2,1,384,384]
    const float* trimap = (const float*)d_in[1];  // gt_trimap   [2,1,384,384]
    const float* image  = (const float*)d_in[2];  // input_image [2,3,384,384]
    float* out = (float*)d_out;
    float4* bout = (float4*)d_ws;                 // NBLK float4 partials

    matting_main<<<NBLK, NTHR, 0, stream>>>(alpha, trimap, image, bout);
    matting_finalize<<<1, 256, 0, stream>>>(bout, out);
}